// Round 1
// baseline (1042.591 us; speedup 1.0000x reference)
//
#include <hip/hip_runtime.h>
#include <cstdint>
#include <cstddef>

#define NTOK 8192
#define DMODEL 1024
#define NEXP 8
#define CAP 2048
#define HFF 2730
#define HFF2 5460
#define KPAD 2752
#define LDA 40   // 32 + 8 pad (bf16 elems) -> 80B row stride, 16B aligned

typedef float f32x4 __attribute__((ext_vector_type(4)));
typedef __attribute__((ext_vector_type(8))) short short8;

__device__ inline unsigned short f2bf(float f) {
  union { float f; unsigned u; } v; v.f = f;
  unsigned u = v.u;
  return (unsigned short)((u + 0x7FFFu + ((u >> 16) & 1u)) >> 16);
}

// ---------------- Router: one wave per token, fp64 accumulation ----------------
__global__ void router_kernel(const float* __restrict__ x,
                              const float* __restrict__ noise,
                              const float* __restrict__ w_route,
                              const float* __restrict__ b_route,
                              const float* __restrict__ w_noise,
                              const float* __restrict__ b_noise,
                              int* __restrict__ topi,
                              float* __restrict__ gates) {
  const int lane = threadIdx.x & 63;
  const int wave = threadIdx.x >> 6;
  const int tok = blockIdx.x * 4 + wave;
  const float* xr = x + (size_t)tok * DMODEL;

  double aR[8], aN[8];
#pragma unroll
  for (int e = 0; e < 8; e++) { aR[e] = 0.0; aN[e] = 0.0; }

  for (int d = lane; d < DMODEL; d += 64) {
    double xv = (double)xr[d];
    const float* wr = w_route + d * 8;
    const float* wn = w_noise + d * 8;
#pragma unroll
    for (int e = 0; e < 8; e++) {
      aR[e] += xv * (double)wr[e];
      aN[e] += xv * (double)wn[e];
    }
  }
#pragma unroll
  for (int off = 32; off > 0; off >>= 1) {
#pragma unroll
    for (int e = 0; e < 8; e++) {
      aR[e] += __shfl_down(aR[e], (unsigned)off, 64);
      aN[e] += __shfl_down(aN[e], (unsigned)off, 64);
    }
  }
  if (lane == 0) {
    double nv[8];
#pragma unroll
    for (int e = 0; e < 8; e++) {
      double lg = aR[e] + (double)b_route[e];
      double ns = aN[e] + (double)b_noise[e];
      double sp = fmax(ns, 0.0) + log1p(exp(-fabs(ns)));  // stable softplus
      nv[e] = lg + (double)noise[(size_t)tok * 8 + e] * sp;
    }
    int i0 = 0;
#pragma unroll
    for (int e = 1; e < 8; e++) if (nv[e] > nv[i0]) i0 = e;
    int i1 = (i0 == 0) ? 1 : 0;
#pragma unroll
    for (int e = 0; e < 8; e++) if (e != i0 && nv[e] > nv[i1]) i1 = e;
    double r = exp(nv[i1] - nv[i0]);
    float g0 = (float)(1.0 / (1.0 + r));
    float g1 = (float)(r / (1.0 + r));
    topi[tok * 2] = i0; topi[tok * 2 + 1] = i1;
    gates[tok * 2] = g0; gates[tok * 2 + 1] = g1;
  }
}

// ---------------- Aux loss: single block reduce ----------------
__global__ void aux_kernel(const int* __restrict__ topi,
                           const float* __restrict__ gates,
                           float* __restrict__ out) {
  const int t = threadIdx.x;
  float s[8];
#pragma unroll
  for (int e = 0; e < 8; e++) s[e] = 0.f;
  for (int i = t; i < NTOK; i += 256) {
    int i0 = topi[2 * i], i1 = topi[2 * i + 1];
    float g0 = gates[2 * i], g1 = gates[2 * i + 1];
#pragma unroll
    for (int e = 0; e < 8; e++)
      s[e] += (i0 == e ? g0 : 0.f) + (i1 == e ? g1 : 0.f);
  }
  __shared__ float sh[256][8];
#pragma unroll
  for (int e = 0; e < 8; e++) sh[t][e] = s[e];
  __syncthreads();
  for (int stride = 128; stride > 0; stride >>= 1) {
    if (t < stride) {
#pragma unroll
      for (int e = 0; e < 8; e++) sh[t][e] += sh[t + stride][e];
    }
    __syncthreads();
  }
  if (t == 0) {
    float aux = 0.f;
#pragma unroll
    for (int e = 0; e < 8; e++) {
      float p = sh[0][e] / (float)NTOK - 0.125f;
      aux += p * p;
    }
    out[(size_t)NTOK * DMODEL] = aux;
  }
}

// ---------------- Dispatch: per-expert ordered capacity scan ----------------
__global__ void dispatch_kernel(const int* __restrict__ topi,
                                const float* __restrict__ gates,
                                int* __restrict__ sel,
                                float* __restrict__ gsel) {
  const int e = blockIdx.x;
  const int t = threadIdx.x;
  const int lane = t & 63;
  const int wave = t >> 6;
  __shared__ int waveSum[4];
  __shared__ int runningS;
  if (t == 0) runningS = 0;
  __syncthreads();

  for (int base = 0; base < NTOK; base += 256) {
    int tok = base + t;
    int i0 = topi[2 * tok], i1 = topi[2 * tok + 1];
    bool hit = (i0 == e) || (i1 == e);
    float g = (i0 == e) ? gates[2 * tok] : gates[2 * tok + 1];
    unsigned long long m = __ballot(hit);
    int prefix = __popcll(m & ((1ull << lane) - 1ull));
    if (lane == 63) waveSum[wave] = prefix + (hit ? 1 : 0);
    __syncthreads();
    int waveOff = 0;
    for (int w = 0; w < wave; w++) waveOff += waveSum[w];
    int pos = runningS + waveOff + prefix;
    if (hit && pos < CAP) { sel[e * CAP + pos] = tok; gsel[e * CAP + pos] = g; }
    __syncthreads();
    if (t == 0) runningS += waveSum[0] + waveSum[1] + waveSum[2] + waveSum[3];
    __syncthreads();
  }
  int total = runningS;
  for (int p = total + t; p < CAP; p += 256) { sel[e * CAP + p] = 0; gsel[e * CAP + p] = 0.f; }
}

// ---------------- Transpose wp [E][1024][5460] f32 -> wpT [E][5460][1024] bf16 ----------------
__global__ void transpose_wp_kernel(const float* __restrict__ wp,
                                    unsigned short* __restrict__ wpT) {
  const int e = blockIdx.z, d0 = blockIdx.y * 32, f0 = blockIdx.x * 32;
  __shared__ unsigned short tile[32][33];
  const int t = threadIdx.x;
  {
    int ld = t >> 3, lf4 = (t & 7) * 4;
    if (f0 + lf4 < HFF2) {
      float4 v = *(const float4*)(wp + (size_t)e * DMODEL * HFF2 + (size_t)(d0 + ld) * HFF2 + f0 + lf4);
      tile[ld][lf4 + 0] = f2bf(v.x);
      tile[ld][lf4 + 1] = f2bf(v.y);
      tile[ld][lf4 + 2] = f2bf(v.z);
      tile[ld][lf4 + 3] = f2bf(v.w);
    }
  }
  __syncthreads();
  {
    int lf = t >> 3, ldq = (t & 7) * 4;
    if (f0 + lf < HFF2) {
      ushort4 o = make_ushort4(tile[ldq + 0][lf], tile[ldq + 1][lf],
                               tile[ldq + 2][lf], tile[ldq + 3][lf]);
      *(ushort4*)(wpT + (size_t)e * HFF2 * DMODEL + (size_t)(f0 + lf) * DMODEL + d0 + ldq) = o;
    }
  }
}

// ---------------- Transpose wd [E][2730][1024] f32 -> wdT [E][1024][2752] bf16 (K zero-padded) ----------------
__global__ void transpose_wd_kernel(const float* __restrict__ wd,
                                    unsigned short* __restrict__ wdT) {
  const int e = blockIdx.z, d0 = blockIdx.y * 32, k0 = blockIdx.x * 32;
  __shared__ unsigned short tile[32][33];
  const int t = threadIdx.x;
  {
    int lk = t >> 3, ld4 = (t & 7) * 4;
    int k = k0 + lk;
    if (k < HFF) {
      float4 v = *(const float4*)(wd + (size_t)e * HFF * DMODEL + (size_t)k * DMODEL + d0 + ld4);
      tile[lk][ld4 + 0] = f2bf(v.x);
      tile[lk][ld4 + 1] = f2bf(v.y);
      tile[lk][ld4 + 2] = f2bf(v.z);
      tile[lk][ld4 + 3] = f2bf(v.w);
    } else {
      tile[lk][ld4 + 0] = 0; tile[lk][ld4 + 1] = 0;
      tile[lk][ld4 + 2] = 0; tile[lk][ld4 + 3] = 0;
    }
  }
  __syncthreads();
  {
    int ld = t >> 3, lkq = (t & 7) * 4;
    ushort4 o = make_ushort4(tile[lkq + 0][ld], tile[lkq + 1][ld],
                             tile[lkq + 2][ld], tile[lkq + 3][ld]);
    *(ushort4*)(wdT + (size_t)e * DMODEL * KPAD + (size_t)(d0 + ld) * KPAD + k0 + lkq) = o;
  }
}

// ---------------- GEMM1: h = silu(X@wp1) * (X@wp2), bf16 MFMA, fused SwiGLU ----------------
__global__ __launch_bounds__(256, 2)
void gemm1_kernel(const float* __restrict__ x,
                  const unsigned short* __restrict__ wpT,
                  const int* __restrict__ sel,
                  unsigned short* __restrict__ h) {
  const int e = blockIdx.z;
  const int m0 = blockIdx.y * 128;
  const int n0 = blockIdx.x * 128;

  __shared__ __align__(16) unsigned short As[128 * LDA];
  __shared__ __align__(16) unsigned short B1s[128 * LDA];
  __shared__ __align__(16) unsigned short B2s[128 * LDA];

  const int t = threadIdx.x;
  const int lane = t & 63;
  const int wave = t >> 6;
  const int wm = (wave >> 1) * 64;
  const int wn = (wave & 1) * 64;
  const int fr = lane & 15;
  const int fq = lane >> 4;

  const int sr = t >> 1;          // staging row 0..127
  const int skc = (t & 1) * 16;   // staging k offset 0/16

  const int tok = sel[e * CAP + m0 + sr];
  const float* xrow = x + (size_t)tok * DMODEL + skc;

  const int g1 = n0 + sr;
  const bool bval = (g1 < HFF);
  const size_t erow = (size_t)e * HFF2;
  const unsigned short* b1row = wpT + (erow + (size_t)(bval ? g1 : 0)) * DMODEL + skc;
  const unsigned short* b2row = wpT + (erow + (size_t)(bval ? (HFF + g1) : 0)) * DMODEL + skc;

  f32x4 acc1[4][4], acc2[4][4];
#pragma unroll
  for (int i = 0; i < 4; i++)
#pragma unroll
    for (int j = 0; j < 4; j++) { acc1[i][j] = (f32x4)0.f; acc2[i][j] = (f32x4)0.f; }

  unsigned short* aDst = As + sr * LDA + skc;
  unsigned short* b1Dst = B1s + sr * LDA + skc;
  unsigned short* b2Dst = B2s + sr * LDA + skc;

  for (int k0 = 0; k0 < DMODEL; k0 += 32) {
    {  // A stage: 16 f32 -> bf16
      const float4* xp = (const float4*)(xrow + k0);
      float4 v0 = xp[0], v1 = xp[1], v2 = xp[2], v3 = xp[3];
      union { short8 v; unsigned short s[8]; } p0, p1;
      p0.s[0] = f2bf(v0.x); p0.s[1] = f2bf(v0.y); p0.s[2] = f2bf(v0.z); p0.s[3] = f2bf(v0.w);
      p0.s[4] = f2bf(v1.x); p0.s[5] = f2bf(v1.y); p0.s[6] = f2bf(v1.z); p0.s[7] = f2bf(v1.w);
      p1.s[0] = f2bf(v2.x); p1.s[1] = f2bf(v2.y); p1.s[2] = f2bf(v2.z); p1.s[3] = f2bf(v2.w);
      p1.s[4] = f2bf(v3.x); p1.s[5] = f2bf(v3.y); p1.s[6] = f2bf(v3.z); p1.s[7] = f2bf(v3.w);
      *(short8*)aDst = p0.v;
      *(short8*)(aDst + 8) = p1.v;
    }
    if (bval) {  // B stages: already bf16, raw 32B copies
      const uint4* b1p = (const uint4*)(b1row + k0);
      *(uint4*)b1Dst = b1p[0];
      *(uint4*)(b1Dst + 8) = b1p[1];
      const uint4* b2p = (const uint4*)(b2row + k0);
      *(uint4*)b2Dst = b2p[0];
      *(uint4*)(b2Dst + 8) = b2p[1];
    } else {
      uint4 z = make_uint4(0, 0, 0, 0);
      *(uint4*)b1Dst = z; *(uint4*)(b1Dst + 8) = z;
      *(uint4*)b2Dst = z; *(uint4*)(b2Dst + 8) = z;
    }
    __syncthreads();

    short8 a[4], b1[4], b2[4];
#pragma unroll
    for (int i = 0; i < 4; i++)
      a[i] = *(const short8*)(As + (wm + i * 16 + fr) * LDA + fq * 8);
#pragma unroll
    for (int j = 0; j < 4; j++) {
      b1[j] = *(const short8*)(B1s + (wn + j * 16 + fr) * LDA + fq * 8);
      b2[j] = *(const short8*)(B2s + (wn + j * 16 + fr) * LDA + fq * 8);
    }
#pragma unroll
    for (int i = 0; i < 4; i++)
#pragma unroll
      for (int j = 0; j < 4; j++) {
        acc1[i][j] = __builtin_amdgcn_mfma_f32_16x16x32_bf16(a[i], b1[j], acc1[i][j], 0, 0, 0);
        acc2[i][j] = __builtin_amdgcn_mfma_f32_16x16x32_bf16(a[i], b2[j], acc2[i][j], 0, 0, 0);
      }
    __syncthreads();
  }

#pragma unroll
  for (int i = 0; i < 4; i++) {
#pragma unroll
    for (int j = 0; j < 4; j++) {
      const int col = n0 + wn + j * 16 + fr;
      if (col < KPAD) {
#pragma unroll
        for (int r = 0; r < 4; r++) {
          const int row = m0 + wm + i * 16 + fq * 4 + r;
          float v1 = acc1[i][j][r], v2 = acc2[i][j][r];
          float hv = (col < HFF) ? (v1 / (1.f + __expf(-v1))) * v2 : 0.f;
          h[((size_t)e * CAP + row) * KPAD + col] = f2bf(hv);
        }
      }
    }
  }
}

// ---------------- GEMM2: out[tok] += gate * (h @ wd), bf16 MFMA + atomic scatter ----------------
__global__ __launch_bounds__(256, 2)
void gemm2_kernel(const unsigned short* __restrict__ h,
                  const unsigned short* __restrict__ wdT,
                  const int* __restrict__ sel,
                  const float* __restrict__ gsel,
                  float* __restrict__ out) {
  const int e = blockIdx.z;
  const int m0 = blockIdx.y * 128;
  const int n0 = blockIdx.x * 128;

  __shared__ __align__(16) unsigned short As[128 * LDA];
  __shared__ __align__(16) unsigned short Bs[128 * LDA];
  __shared__ int selS[128];
  __shared__ float gS[128];

  const int t = threadIdx.x;
  if (t < 128) { selS[t] = sel[e * CAP + m0 + t]; gS[t] = gsel[e * CAP + m0 + t]; }

  const int lane = t & 63;
  const int wave = t >> 6;
  const int wm = (wave >> 1) * 64;
  const int wn = (wave & 1) * 64;
  const int fr = lane & 15;
  const int fq = lane >> 4;

  const int sr = t >> 1;
  const int skc = (t & 1) * 16;

  const unsigned short* arow = h + ((size_t)e * CAP + m0 + sr) * KPAD + skc;
  const unsigned short* brow = wdT + ((size_t)e * DMODEL + n0 + sr) * KPAD + skc;

  f32x4 acc[4][4];
#pragma unroll
  for (int i = 0; i < 4; i++)
#pragma unroll
    for (int j = 0; j < 4; j++) acc[i][j] = (f32x4)0.f;

  unsigned short* aDst = As + sr * LDA + skc;
  unsigned short* bDst = Bs + sr * LDA + skc;

  for (int k0 = 0; k0 < KPAD; k0 += 32) {
    {
      const uint4* ap = (const uint4*)(arow + k0);
      *(uint4*)aDst = ap[0];
      *(uint4*)(aDst + 8) = ap[1];
      const uint4* bp = (const uint4*)(brow + k0);
      *(uint4*)bDst = bp[0];
      *(uint4*)(bDst + 8) = bp[1];
    }
    __syncthreads();

    short8 a[4], b[4];
#pragma unroll
    for (int i = 0; i < 4; i++)
      a[i] = *(const short8*)(As + (wm + i * 16 + fr) * LDA + fq * 8);
#pragma unroll
    for (int j = 0; j < 4; j++)
      b[j] = *(const short8*)(Bs + (wn + j * 16 + fr) * LDA + fq * 8);
#pragma unroll
    for (int i = 0; i < 4; i++)
#pragma unroll
      for (int j = 0; j < 4; j++)
        acc[i][j] = __builtin_amdgcn_mfma_f32_16x16x32_bf16(a[i], b[j], acc[i][j], 0, 0, 0);
    __syncthreads();
  }

#pragma unroll
  for (int i = 0; i < 4; i++) {
#pragma unroll
    for (int j = 0; j < 4; j++) {
      const int col = n0 + wn + j * 16 + fr;
#pragma unroll
      for (int r = 0; r < 4; r++) {
        const int rowL = wm + i * 16 + fq * 4 + r;
        float g = gS[rowL];
        if (g != 0.f) {
          int token = selS[rowL];
          atomicAdd(&out[(size_t)token * DMODEL + col], acc[i][j][r] * g);
        }
      }
    }
  }
}

// ---------------- launch ----------------
extern "C" void kernel_launch(void* const* d_in, const int* in_sizes, int n_in,
                              void* d_out, int out_size, void* d_ws, size_t ws_size,
                              hipStream_t stream) {
  const float* x = (const float*)d_in[0];
  const float* noise = (const float*)d_in[1];
  const float* w_route = (const float*)d_in[2];
  const float* b_route = (const float*)d_in[3];
  const float* w_noise = (const float*)d_in[4];
  const float* b_noise = (const float*)d_in[5];
  const float* w_proj = (const float*)d_in[6];
  const float* w_down = (const float*)d_in[7];
  float* out = (float*)d_out;

  char* ws = (char*)d_ws;
  const size_t WT_BYTES = (size_t)NEXP * HFF2 * DMODEL * 2;  // 89.4 MB (wpT, later reused as wdT)
  const size_t H_BYTES = (size_t)NEXP * CAP * KPAD * 2;      // 90.2 MB
  unsigned short* wT = (unsigned short*)ws;
  unsigned short* hbuf = (unsigned short*)(ws + WT_BYTES);
  char* p = ws + WT_BYTES + H_BYTES;
  int* sel = (int*)p;          p += (size_t)NEXP * CAP * 4;
  float* gsel = (float*)p;     p += (size_t)NEXP * CAP * 4;
  int* topi = (int*)p;         p += (size_t)NTOK * 2 * 4;
  float* gates = (float*)p;

  hipMemsetAsync(d_out, 0, (size_t)out_size * sizeof(float), stream);

  hipLaunchKernelGGL(router_kernel, dim3(NTOK / 4), dim3(256), 0, stream,
                     x, noise, w_route, b_route, w_noise, b_noise, topi, gates);
  hipLaunchKernelGGL(aux_kernel, dim3(1), dim3(256), 0, stream, topi, gates, out);
  hipLaunchKernelGGL(dispatch_kernel, dim3(NEXP), dim3(256), 0, stream, topi, gates, sel, gsel);
  hipLaunchKernelGGL(transpose_wp_kernel, dim3(171, 32, NEXP), dim3(256), 0, stream, w_proj, wT);
  hipLaunchKernelGGL(gemm1_kernel, dim3(22, 16, NEXP), dim3(256), 0, stream, x, wT, sel, hbuf);
  hipLaunchKernelGGL(transpose_wd_kernel, dim3(KPAD / 32, DMODEL / 32, NEXP), dim3(256), 0, stream, w_down, wT);
  hipLaunchKernelGGL(gemm2_kernel, dim3(DMODEL / 128, CAP / 128, NEXP), dim3(256), 0, stream,
                     hbuf, wT, sel, gsel, out);
}

// Round 2
// 927.060 us; speedup vs baseline: 1.1246x; 1.1246x over previous
//
#include <hip/hip_runtime.h>
#include <cstdint>
#include <cstddef>

#define NTOK 8192
#define DMODEL 1024
#define NEXP 8
#define CAP 2048
#define HFF 2730
#define HFF2 5460
#define KPAD 2752

typedef float f32x4 __attribute__((ext_vector_type(4)));
typedef __attribute__((ext_vector_type(8))) short short8;

__device__ inline unsigned short f2bf(float f) {
  union { float f; unsigned u; } v; v.f = f;
  unsigned u = v.u;
  return (unsigned short)((u + 0x7FFFu + ((u >> 16) & 1u)) >> 16);
}

// global -> LDS direct DMA, 16 B per lane. LDS dest must be wave-uniform base;
// each lane lands at base + lane*16. Global src may be per-lane (gather OK).
typedef __attribute__((address_space(1))) const void g_void;
typedef __attribute__((address_space(3))) void l_void;
__device__ __forceinline__ void dma16(const void* g, void* l) {
  __builtin_amdgcn_global_load_lds((g_void*)g, (l_void*)l, 16, 0, 0);
}

// ---------------- cast x f32 -> bf16 (stored in d_out scratch region) ----------------
__global__ void cast_x_kernel(const float* __restrict__ x, unsigned short* __restrict__ xb) {
  size_t i = ((size_t)blockIdx.x * 256 + threadIdx.x) * 8;
  float4 v0 = *(const float4*)(x + i);
  float4 v1 = *(const float4*)(x + i + 4);
  union { short8 v; unsigned short s[8]; } p;
  p.s[0] = f2bf(v0.x); p.s[1] = f2bf(v0.y); p.s[2] = f2bf(v0.z); p.s[3] = f2bf(v0.w);
  p.s[4] = f2bf(v1.x); p.s[5] = f2bf(v1.y); p.s[6] = f2bf(v1.z); p.s[7] = f2bf(v1.w);
  *(short8*)(xb + i) = p.v;
}

// ---------------- Router: one wave per token, fp64 accumulation ----------------
__global__ void router_kernel(const float* __restrict__ x,
                              const float* __restrict__ noise,
                              const float* __restrict__ w_route,
                              const float* __restrict__ b_route,
                              const float* __restrict__ w_noise,
                              const float* __restrict__ b_noise,
                              int* __restrict__ topi,
                              float* __restrict__ gates) {
  const int lane = threadIdx.x & 63;
  const int wave = threadIdx.x >> 6;
  const int tok = blockIdx.x * 4 + wave;
  const float* xr = x + (size_t)tok * DMODEL;

  double aR[8], aN[8];
#pragma unroll
  for (int e = 0; e < 8; e++) { aR[e] = 0.0; aN[e] = 0.0; }

  for (int d = lane; d < DMODEL; d += 64) {
    double xv = (double)xr[d];
    const float* wr = w_route + d * 8;
    const float* wn = w_noise + d * 8;
#pragma unroll
    for (int e = 0; e < 8; e++) {
      aR[e] += xv * (double)wr[e];
      aN[e] += xv * (double)wn[e];
    }
  }
#pragma unroll
  for (int off = 32; off > 0; off >>= 1) {
#pragma unroll
    for (int e = 0; e < 8; e++) {
      aR[e] += __shfl_down(aR[e], (unsigned)off, 64);
      aN[e] += __shfl_down(aN[e], (unsigned)off, 64);
    }
  }
  if (lane == 0) {
    double nv[8];
#pragma unroll
    for (int e = 0; e < 8; e++) {
      double lg = aR[e] + (double)b_route[e];
      double ns = aN[e] + (double)b_noise[e];
      double sp = fmax(ns, 0.0) + log1p(exp(-fabs(ns)));  // stable softplus
      nv[e] = lg + (double)noise[(size_t)tok * 8 + e] * sp;
    }
    int i0 = 0;
#pragma unroll
    for (int e = 1; e < 8; e++) if (nv[e] > nv[i0]) i0 = e;
    int i1 = (i0 == 0) ? 1 : 0;
#pragma unroll
    for (int e = 0; e < 8; e++) if (e != i0 && nv[e] > nv[i1]) i1 = e;
    double r = exp(nv[i1] - nv[i0]);
    float g0 = (float)(1.0 / (1.0 + r));
    float g1 = (float)(r / (1.0 + r));
    topi[tok * 2] = i0; topi[tok * 2 + 1] = i1;
    gates[tok * 2] = g0; gates[tok * 2 + 1] = g1;
  }
}

// ---------------- Aux loss: single block reduce (runs AFTER out memset) ----------------
__global__ void aux_kernel(const int* __restrict__ topi,
                           const float* __restrict__ gates,
                           float* __restrict__ out) {
  const int t = threadIdx.x;
  float s[8];
#pragma unroll
  for (int e = 0; e < 8; e++) s[e] = 0.f;
  for (int i = t; i < NTOK; i += 256) {
    int i0 = topi[2 * i], i1 = topi[2 * i + 1];
    float g0 = gates[2 * i], g1 = gates[2 * i + 1];
#pragma unroll
    for (int e = 0; e < 8; e++)
      s[e] += (i0 == e ? g0 : 0.f) + (i1 == e ? g1 : 0.f);
  }
  __shared__ float sh[256][8];
#pragma unroll
  for (int e = 0; e < 8; e++) sh[t][e] = s[e];
  __syncthreads();
  for (int stride = 128; stride > 0; stride >>= 1) {
    if (t < stride) {
#pragma unroll
      for (int e = 0; e < 8; e++) sh[t][e] += sh[t + stride][e];
    }
    __syncthreads();
  }
  if (t == 0) {
    float aux = 0.f;
#pragma unroll
    for (int e = 0; e < 8; e++) {
      float p = sh[0][e] / (float)NTOK - 0.125f;
      aux += p * p;
    }
    out[(size_t)NTOK * DMODEL] = aux;
  }
}

// ---------------- Dispatch: per-expert ordered capacity scan ----------------
__global__ void dispatch_kernel(const int* __restrict__ topi,
                                const float* __restrict__ gates,
                                int* __restrict__ sel,
                                float* __restrict__ gsel) {
  const int e = blockIdx.x;
  const int t = threadIdx.x;
  const int lane = t & 63;
  const int wave = t >> 6;
  __shared__ int waveSum[4];
  __shared__ int runningS;
  if (t == 0) runningS = 0;
  __syncthreads();

  for (int base = 0; base < NTOK; base += 256) {
    int tok = base + t;
    int i0 = topi[2 * tok], i1 = topi[2 * tok + 1];
    bool hit = (i0 == e) || (i1 == e);
    float g = (i0 == e) ? gates[2 * tok] : gates[2 * tok + 1];
    unsigned long long m = __ballot(hit);
    int prefix = __popcll(m & ((1ull << lane) - 1ull));
    if (lane == 63) waveSum[wave] = prefix + (hit ? 1 : 0);
    __syncthreads();
    int waveOff = 0;
    for (int w = 0; w < wave; w++) waveOff += waveSum[w];
    int pos = runningS + waveOff + prefix;
    if (hit && pos < CAP) { sel[e * CAP + pos] = tok; gsel[e * CAP + pos] = g; }
    __syncthreads();
    if (t == 0) runningS += waveSum[0] + waveSum[1] + waveSum[2] + waveSum[3];
    __syncthreads();
  }
  int total = runningS;
  for (int p = total + t; p < CAP; p += 256) { sel[e * CAP + p] = 0; gsel[e * CAP + p] = 0.f; }
}

// ---------------- Transpose wp [E][1024][5460] f32 -> wpT [E][5460][1024] bf16 ----------------
__global__ void transpose_wp_kernel(const float* __restrict__ wp,
                                    unsigned short* __restrict__ wpT) {
  const int e = blockIdx.z, d0 = blockIdx.y * 32, f0 = blockIdx.x * 32;
  __shared__ unsigned short tile[32][33];
  const int t = threadIdx.x;
  {
    int ld = t >> 3, lf4 = (t & 7) * 4;
    if (f0 + lf4 < HFF2) {
      float4 v = *(const float4*)(wp + (size_t)e * DMODEL * HFF2 + (size_t)(d0 + ld) * HFF2 + f0 + lf4);
      tile[ld][lf4 + 0] = f2bf(v.x);
      tile[ld][lf4 + 1] = f2bf(v.y);
      tile[ld][lf4 + 2] = f2bf(v.z);
      tile[ld][lf4 + 3] = f2bf(v.w);
    }
  }
  __syncthreads();
  {
    int lf = t >> 3, ldq = (t & 7) * 4;
    if (f0 + lf < HFF2) {
      ushort4 o = make_ushort4(tile[ldq + 0][lf], tile[ldq + 1][lf],
                               tile[ldq + 2][lf], tile[ldq + 3][lf]);
      *(ushort4*)(wpT + (size_t)e * HFF2 * DMODEL + (size_t)(f0 + lf) * DMODEL + d0 + ldq) = o;
    }
  }
}

// ---------------- Transpose wd [E][2730][1024] f32 -> wdT [E][1024][2752] bf16 (K zero-padded) ----------------
__global__ void transpose_wd_kernel(const float* __restrict__ wd,
                                    unsigned short* __restrict__ wdT) {
  const int e = blockIdx.z, d0 = blockIdx.y * 32, k0 = blockIdx.x * 32;
  __shared__ unsigned short tile[32][33];
  const int t = threadIdx.x;
  {
    int lk = t >> 3, ld4 = (t & 7) * 4;
    int k = k0 + lk;
    if (k < HFF) {
      float4 v = *(const float4*)(wd + (size_t)e * HFF * DMODEL + (size_t)k * DMODEL + d0 + ld4);
      tile[lk][ld4 + 0] = f2bf(v.x);
      tile[lk][ld4 + 1] = f2bf(v.y);
      tile[lk][ld4 + 2] = f2bf(v.z);
      tile[lk][ld4 + 3] = f2bf(v.w);
    } else {
      tile[lk][ld4 + 0] = 0; tile[lk][ld4 + 1] = 0;
      tile[lk][ld4 + 2] = 0; tile[lk][ld4 + 3] = 0;
    }
  }
  __syncthreads();
  {
    int ld = t >> 3, lkq = (t & 7) * 4;
    ushort4 o = make_ushort4(tile[lkq + 0][ld], tile[lkq + 1][ld],
                             tile[lkq + 2][ld], tile[lkq + 3][ld]);
    *(ushort4*)(wdT + (size_t)e * DMODEL * KPAD + (size_t)(d0 + ld) * KPAD + k0 + lkq) = o;
  }
}

// ---------------- GEMM1: h = silu(X@wp1) * (X@wp2), global_load_lds staging ----------------
__global__ __launch_bounds__(256, 2)
void gemm1_kernel(const unsigned short* __restrict__ xb,
                  const unsigned short* __restrict__ wpT,
                  const int* __restrict__ sel,
                  unsigned short* __restrict__ h) {
  const int e = blockIdx.z;
  const int m0 = blockIdx.y * 128;
  const int n0 = blockIdx.x * 128;

  // unpadded: row stride 32 elems (64 B) — required by global_load_lds lane order
  __shared__ __align__(16) unsigned short As[128 * 32];
  __shared__ __align__(16) unsigned short B1s[128 * 32];
  __shared__ __align__(16) unsigned short B2s[128 * 32];

  const int t = threadIdx.x;
  const int lane = t & 63;
  const int w = t >> 6;
  const int wm = (w >> 1) * 64;
  const int wn = (w & 1) * 64;
  const int fr = lane & 15;
  const int fq = lane >> 4;

  // staging: thread t covers (row = t>>2 [+64], 8 elems at seg)
  const int r0 = t >> 2;
  const int seg = (t & 3) * 8;
  const int tok0 = sel[e * CAP + m0 + r0];
  const int tok1 = sel[e * CAP + m0 + 64 + r0];
  const unsigned short* ga0 = xb + (size_t)tok0 * DMODEL + seg;
  const unsigned short* ga1 = xb + (size_t)tok1 * DMODEL + seg;
  const size_t ebase = (size_t)e * HFF2;
  int c0 = n0 + r0;       if (c0 >= HFF) c0 = HFF - 1;   // clamp: garbage cols discarded in epilogue
  int c1 = n0 + 64 + r0;  if (c1 >= HFF) c1 = HFF - 1;
  const unsigned short* gb10 = wpT + (ebase + (size_t)c0) * DMODEL + seg;
  const unsigned short* gb11 = wpT + (ebase + (size_t)c1) * DMODEL + seg;
  const unsigned short* gb20 = wpT + (ebase + (size_t)(HFF + c0)) * DMODEL + seg;
  const unsigned short* gb21 = wpT + (ebase + (size_t)(HFF + c1)) * DMODEL + seg;

  // wave-uniform LDS dest bases (issue 0: rows 0-63, issue 1: rows 64-127)
  unsigned short* aD0 = As + (w * 16) * 32;
  unsigned short* aD1 = As + (64 + w * 16) * 32;
  unsigned short* b1D0 = B1s + (w * 16) * 32;
  unsigned short* b1D1 = B1s + (64 + w * 16) * 32;
  unsigned short* b2D0 = B2s + (w * 16) * 32;
  unsigned short* b2D1 = B2s + (64 + w * 16) * 32;

  f32x4 acc1[4][4], acc2[4][4];
#pragma unroll
  for (int i = 0; i < 4; i++)
#pragma unroll
    for (int j = 0; j < 4; j++) { acc1[i][j] = (f32x4)0.f; acc2[i][j] = (f32x4)0.f; }

  for (int k0 = 0; k0 < DMODEL; k0 += 32) {
    dma16(ga0 + k0, aD0);
    dma16(ga1 + k0, aD1);
    dma16(gb10 + k0, b1D0);
    dma16(gb11 + k0, b1D1);
    dma16(gb20 + k0, b2D0);
    dma16(gb21 + k0, b2D1);
    __syncthreads();

    short8 a[4], b1[4], b2[4];
#pragma unroll
    for (int i = 0; i < 4; i++)
      a[i] = *(const short8*)(As + (wm + i * 16 + fr) * 32 + fq * 8);
#pragma unroll
    for (int j = 0; j < 4; j++) {
      b1[j] = *(const short8*)(B1s + (wn + j * 16 + fr) * 32 + fq * 8);
      b2[j] = *(const short8*)(B2s + (wn + j * 16 + fr) * 32 + fq * 8);
    }
#pragma unroll
    for (int i = 0; i < 4; i++)
#pragma unroll
      for (int j = 0; j < 4; j++) {
        acc1[i][j] = __builtin_amdgcn_mfma_f32_16x16x32_bf16(a[i], b1[j], acc1[i][j], 0, 0, 0);
        acc2[i][j] = __builtin_amdgcn_mfma_f32_16x16x32_bf16(a[i], b2[j], acc2[i][j], 0, 0, 0);
      }
    __syncthreads();
  }

#pragma unroll
  for (int i = 0; i < 4; i++) {
#pragma unroll
    for (int j = 0; j < 4; j++) {
      const int col = n0 + wn + j * 16 + fr;
      if (col < KPAD) {
#pragma unroll
        for (int r = 0; r < 4; r++) {
          const int row = m0 + wm + i * 16 + fq * 4 + r;
          float v1 = acc1[i][j][r], v2 = acc2[i][j][r];
          float hv = (col < HFF) ? (v1 / (1.f + __expf(-v1))) * v2 : 0.f;
          h[((size_t)e * CAP + row) * KPAD + col] = f2bf(hv);
        }
      }
    }
  }
}

// ---------------- GEMM2: out[tok] += gate * (h @ wd), global_load_lds staging ----------------
__global__ __launch_bounds__(256, 2)
void gemm2_kernel(const unsigned short* __restrict__ h,
                  const unsigned short* __restrict__ wdT,
                  const int* __restrict__ sel,
                  const float* __restrict__ gsel,
                  float* __restrict__ out) {
  const int e = blockIdx.z;
  const int m0 = blockIdx.y * 128;
  const int n0 = blockIdx.x * 128;

  __shared__ __align__(16) unsigned short As[128 * 32];
  __shared__ __align__(16) unsigned short Bs[128 * 32];
  __shared__ int selS[128];
  __shared__ float gS[128];

  const int t = threadIdx.x;
  if (t < 128) { selS[t] = sel[e * CAP + m0 + t]; gS[t] = gsel[e * CAP + m0 + t]; }

  const int lane = t & 63;
  const int w = t >> 6;
  const int wm = (w >> 1) * 64;
  const int wn = (w & 1) * 64;
  const int fr = lane & 15;
  const int fq = lane >> 4;

  const int r0 = t >> 2;
  const int seg = (t & 3) * 8;
  const unsigned short* ga0 = h + ((size_t)e * CAP + m0 + r0) * KPAD + seg;
  const unsigned short* ga1 = h + ((size_t)e * CAP + m0 + 64 + r0) * KPAD + seg;
  const unsigned short* gb0 = wdT + ((size_t)e * DMODEL + n0 + r0) * KPAD + seg;
  const unsigned short* gb1 = wdT + ((size_t)e * DMODEL + n0 + 64 + r0) * KPAD + seg;

  unsigned short* aD0 = As + (w * 16) * 32;
  unsigned short* aD1 = As + (64 + w * 16) * 32;
  unsigned short* bD0 = Bs + (w * 16) * 32;
  unsigned short* bD1 = Bs + (64 + w * 16) * 32;

  f32x4 acc[4][4];
#pragma unroll
  for (int i = 0; i < 4; i++)
#pragma unroll
    for (int j = 0; j < 4; j++) acc[i][j] = (f32x4)0.f;

  for (int k0 = 0; k0 < KPAD; k0 += 32) {
    dma16(ga0 + k0, aD0);
    dma16(ga1 + k0, aD1);
    dma16(gb0 + k0, bD0);
    dma16(gb1 + k0, bD1);
    __syncthreads();

    short8 a[4], b[4];
#pragma unroll
    for (int i = 0; i < 4; i++)
      a[i] = *(const short8*)(As + (wm + i * 16 + fr) * 32 + fq * 8);
#pragma unroll
    for (int j = 0; j < 4; j++)
      b[j] = *(const short8*)(Bs + (wn + j * 16 + fr) * 32 + fq * 8);
#pragma unroll
    for (int i = 0; i < 4; i++)
#pragma unroll
      for (int j = 0; j < 4; j++)
        acc[i][j] = __builtin_amdgcn_mfma_f32_16x16x32_bf16(a[i], b[j], acc[i][j], 0, 0, 0);
    __syncthreads();
  }

#pragma unroll
  for (int i = 0; i < 4; i++) {
#pragma unroll
    for (int j = 0; j < 4; j++) {
      const int col = n0 + wn + j * 16 + fr;
#pragma unroll
      for (int r = 0; r < 4; r++) {
        const int rowL = wm + i * 16 + fq * 4 + r;
        float g = gS[rowL];
        if (g != 0.f) {
          int token = selS[rowL];
          atomicAdd(&out[(size_t)token * DMODEL + col], acc[i][j][r] * g);
        }
      }
    }
  }
}

// ---------------- launch ----------------
extern "C" void kernel_launch(void* const* d_in, const int* in_sizes, int n_in,
                              void* d_out, int out_size, void* d_ws, size_t ws_size,
                              hipStream_t stream) {
  const float* x = (const float*)d_in[0];
  const float* noise = (const float*)d_in[1];
  const float* w_route = (const float*)d_in[2];
  const float* b_route = (const float*)d_in[3];
  const float* w_noise = (const float*)d_in[4];
  const float* b_noise = (const float*)d_in[5];
  const float* w_proj = (const float*)d_in[6];
  const float* w_down = (const float*)d_in[7];
  float* out = (float*)d_out;

  char* ws = (char*)d_ws;
  const size_t WT_BYTES = (size_t)NEXP * HFF2 * DMODEL * 2;  // 89.4 MB (wpT, later reused as wdT)
  const size_t H_BYTES = (size_t)NEXP * CAP * KPAD * 2;      // 90.2 MB
  unsigned short* wT = (unsigned short*)ws;
  unsigned short* hbuf = (unsigned short*)(ws + WT_BYTES);
  char* p = ws + WT_BYTES + H_BYTES;
  int* sel = (int*)p;          p += (size_t)NEXP * CAP * 4;
  float* gsel = (float*)p;     p += (size_t)NEXP * CAP * 4;
  int* topi = (int*)p;         p += (size_t)NTOK * 2 * 4;
  float* gates = (float*)p;

  // xb (bf16 x, 16.8 MB) lives in d_out until gemm1 is done; out is re-zeroed after.
  unsigned short* xb = (unsigned short*)d_out;

  hipLaunchKernelGGL(cast_x_kernel, dim3(NTOK * DMODEL / (256 * 8)), dim3(256), 0, stream, x, xb);
  hipLaunchKernelGGL(router_kernel, dim3(NTOK / 4), dim3(256), 0, stream,
                     x, noise, w_route, b_route, w_noise, b_noise, topi, gates);
  hipLaunchKernelGGL(dispatch_kernel, dim3(NEXP), dim3(256), 0, stream, topi, gates, sel, gsel);
  hipLaunchKernelGGL(transpose_wp_kernel, dim3(171, 32, NEXP), dim3(256), 0, stream, w_proj, wT);
  hipLaunchKernelGGL(gemm1_kernel, dim3(22, 16, NEXP), dim3(256), 0, stream, xb, wT, sel, hbuf);

  hipMemsetAsync(d_out, 0, (size_t)out_size * sizeof(float), stream);  // xb dead; zero for accumulation
  hipLaunchKernelGGL(aux_kernel, dim3(1), dim3(256), 0, stream, topi, gates, out);
  hipLaunchKernelGGL(transpose_wd_kernel, dim3(KPAD / 32, DMODEL / 32, NEXP), dim3(256), 0, stream, w_down, wT);
  hipLaunchKernelGGL(gemm2_kernel, dim3(DMODEL / 128, CAP / 128, NEXP), dim3(256), 0, stream,
                     hbuf, wT, sel, gsel, out);
}

// Round 3
// 850.190 us; speedup vs baseline: 1.2263x; 1.0904x over previous
//
#include <hip/hip_runtime.h>
#include <cstdint>
#include <cstddef>

#define NTOK 8192
#define DMODEL 1024
#define NEXP 8
#define CAP 2048
#define HFF 2730
#define HFF2 5460
#define KPAD 2752

typedef float f32x4 __attribute__((ext_vector_type(4)));
typedef __attribute__((ext_vector_type(8))) short short8;

__device__ inline unsigned short f2bf(float f) {
  union { float f; unsigned u; } v; v.f = f;
  unsigned u = v.u;
  return (unsigned short)((u + 0x7FFFu + ((u >> 16) & 1u)) >> 16);
}
__device__ inline float bf2f(unsigned short s) {
  union { unsigned u; float f; } v; v.u = ((unsigned)s) << 16; return v.f;
}

// global -> LDS direct DMA, 16 B per lane. LDS dest: wave-uniform base + lane*16.
typedef __attribute__((address_space(1))) const void g_void;
typedef __attribute__((address_space(3))) void l_void;
__device__ __forceinline__ void dma16(const void* g, void* l) {
  __builtin_amdgcn_global_load_lds((g_void*)g, (l_void*)l, 16, 0, 0);
}

// ---------------- cast x f32 -> bf16 (stored in d_out scratch region) ----------------
__global__ void cast_x_kernel(const float* __restrict__ x, unsigned short* __restrict__ xb) {
  size_t i = ((size_t)blockIdx.x * 256 + threadIdx.x) * 8;
  float4 v0 = *(const float4*)(x + i);
  float4 v1 = *(const float4*)(x + i + 4);
  union { short8 v; unsigned short s[8]; } p;
  p.s[0] = f2bf(v0.x); p.s[1] = f2bf(v0.y); p.s[2] = f2bf(v0.z); p.s[3] = f2bf(v0.w);
  p.s[4] = f2bf(v1.x); p.s[5] = f2bf(v1.y); p.s[6] = f2bf(v1.z); p.s[7] = f2bf(v1.w);
  *(short8*)(xb + i) = p.v;
}

// ---------------- Router: one wave per token, fp64 accumulation ----------------
__global__ void router_kernel(const float* __restrict__ x,
                              const float* __restrict__ noise,
                              const float* __restrict__ w_route,
                              const float* __restrict__ b_route,
                              const float* __restrict__ w_noise,
                              const float* __restrict__ b_noise,
                              int* __restrict__ topi,
                              float* __restrict__ gates) {
  const int lane = threadIdx.x & 63;
  const int wave = threadIdx.x >> 6;
  const int tok = blockIdx.x * 4 + wave;
  const float* xr = x + (size_t)tok * DMODEL;

  double aR[8], aN[8];
#pragma unroll
  for (int e = 0; e < 8; e++) { aR[e] = 0.0; aN[e] = 0.0; }

  for (int d = lane; d < DMODEL; d += 64) {
    double xv = (double)xr[d];
    const float* wr = w_route + d * 8;
    const float* wn = w_noise + d * 8;
#pragma unroll
    for (int e = 0; e < 8; e++) {
      aR[e] += xv * (double)wr[e];
      aN[e] += xv * (double)wn[e];
    }
  }
#pragma unroll
  for (int off = 32; off > 0; off >>= 1) {
#pragma unroll
    for (int e = 0; e < 8; e++) {
      aR[e] += __shfl_down(aR[e], (unsigned)off, 64);
      aN[e] += __shfl_down(aN[e], (unsigned)off, 64);
    }
  }
  if (lane == 0) {
    double nv[8];
#pragma unroll
    for (int e = 0; e < 8; e++) {
      double lg = aR[e] + (double)b_route[e];
      double ns = aN[e] + (double)b_noise[e];
      double sp = fmax(ns, 0.0) + log1p(exp(-fabs(ns)));  // stable softplus
      nv[e] = lg + (double)noise[(size_t)tok * 8 + e] * sp;
    }
    int i0 = 0;
#pragma unroll
    for (int e = 1; e < 8; e++) if (nv[e] > nv[i0]) i0 = e;
    int i1 = (i0 == 0) ? 1 : 0;
#pragma unroll
    for (int e = 0; e < 8; e++) if (e != i0 && nv[e] > nv[i1]) i1 = e;
    double r = exp(nv[i1] - nv[i0]);
    float g0 = (float)(1.0 / (1.0 + r));
    float g1 = (float)(r / (1.0 + r));
    topi[tok * 2] = i0; topi[tok * 2 + 1] = i1;
    gates[tok * 2] = g0; gates[tok * 2 + 1] = g1;
  }
}

// ---------------- Aux loss ----------------
__global__ void aux_kernel(const int* __restrict__ topi,
                           const float* __restrict__ gates,
                           float* __restrict__ out) {
  const int t = threadIdx.x;
  float s[8];
#pragma unroll
  for (int e = 0; e < 8; e++) s[e] = 0.f;
  for (int i = t; i < NTOK; i += 256) {
    int i0 = topi[2 * i], i1 = topi[2 * i + 1];
    float g0 = gates[2 * i], g1 = gates[2 * i + 1];
#pragma unroll
    for (int e = 0; e < 8; e++)
      s[e] += (i0 == e ? g0 : 0.f) + (i1 == e ? g1 : 0.f);
  }
  __shared__ float sh[256][8];
#pragma unroll
  for (int e = 0; e < 8; e++) sh[t][e] = s[e];
  __syncthreads();
  for (int stride = 128; stride > 0; stride >>= 1) {
    if (t < stride) {
#pragma unroll
      for (int e = 0; e < 8; e++) sh[t][e] += sh[t + stride][e];
    }
    __syncthreads();
  }
  if (t == 0) {
    float aux = 0.f;
#pragma unroll
    for (int e = 0; e < 8; e++) {
      float p = sh[0][e] / (float)NTOK - 0.125f;
      aux += p * p;
    }
    out[(size_t)NTOK * DMODEL] = aux;
  }
}

// ---------------- Dispatch: per-expert ordered capacity scan + slot map ----------------
__global__ void dispatch_kernel(const int* __restrict__ topi,
                                const float* __restrict__ gates,
                                int* __restrict__ sel,
                                float* __restrict__ gsel,
                                int* __restrict__ slot) {
  const int e = blockIdx.x;
  const int t = threadIdx.x;
  const int lane = t & 63;
  const int w = t >> 6;
  __shared__ int waveCnt[16];
  __shared__ int runningS;
  if (t == 0) runningS = 0;
  __syncthreads();

  for (int base = 0; base < NTOK; base += 1024) {
    int tok = base + t;
    int i0 = topi[2 * tok], i1 = topi[2 * tok + 1];
    bool hit = (i0 == e) || (i1 == e);
    int kth = (i0 == e) ? 0 : 1;
    float g = gates[2 * tok + kth];
    unsigned long long m = __ballot(hit);
    int prefix = __popcll(m & ((1ull << lane) - 1ull));
    if (lane == 63) waveCnt[w] = prefix + (hit ? 1 : 0);
    __syncthreads();
    int off = runningS;
    for (int ww = 0; ww < w; ww++) off += waveCnt[ww];
    int pos = off + prefix;
    if (hit) {
      if (pos < CAP) {
        sel[e * CAP + pos] = tok; gsel[e * CAP + pos] = g;
        slot[2 * tok + kth] = pos;
      } else {
        slot[2 * tok + kth] = -1;
      }
    }
    __syncthreads();
    if (t == 0) {
      int sacc = 0;
#pragma unroll
      for (int ww = 0; ww < 16; ww++) sacc += waveCnt[ww];
      runningS += sacc;
    }
    __syncthreads();
  }
  for (int p = runningS + t; p < CAP; p += 1024) { sel[e * CAP + p] = 0; gsel[e * CAP + p] = 0.f; }
}

// ---------------- Transpose wp [E][1024][5460] f32 -> wpT [E][5460][1024] bf16 ----------------
__global__ void transpose_wp_kernel(const float* __restrict__ wp,
                                    unsigned short* __restrict__ wpT) {
  const int e = blockIdx.z, d0 = blockIdx.y * 32, f0 = blockIdx.x * 32;
  __shared__ unsigned short tile[32][33];
  const int t = threadIdx.x;
  {
    int ld = t >> 3, lf4 = (t & 7) * 4;
    if (f0 + lf4 < HFF2) {
      float4 v = *(const float4*)(wp + (size_t)e * DMODEL * HFF2 + (size_t)(d0 + ld) * HFF2 + f0 + lf4);
      tile[ld][lf4 + 0] = f2bf(v.x);
      tile[ld][lf4 + 1] = f2bf(v.y);
      tile[ld][lf4 + 2] = f2bf(v.z);
      tile[ld][lf4 + 3] = f2bf(v.w);
    }
  }
  __syncthreads();
  {
    int lf = t >> 3, ldq = (t & 7) * 4;
    if (f0 + lf < HFF2) {
      ushort4 o = make_ushort4(tile[ldq + 0][lf], tile[ldq + 1][lf],
                               tile[ldq + 2][lf], tile[ldq + 3][lf]);
      *(ushort4*)(wpT + (size_t)e * HFF2 * DMODEL + (size_t)(f0 + lf) * DMODEL + d0 + ldq) = o;
    }
  }
}

// ---------------- Transpose wd [E][2730][1024] f32 -> wdT [E][1024][2752] bf16 ----------------
__global__ void transpose_wd_kernel(const float* __restrict__ wd,
                                    unsigned short* __restrict__ wdT) {
  const int e = blockIdx.z, d0 = blockIdx.y * 32, k0 = blockIdx.x * 32;
  __shared__ unsigned short tile[32][33];
  const int t = threadIdx.x;
  {
    int lk = t >> 3, ld4 = (t & 7) * 4;
    int k = k0 + lk;
    if (k < HFF) {
      float4 v = *(const float4*)(wd + (size_t)e * HFF * DMODEL + (size_t)k * DMODEL + d0 + ld4);
      tile[lk][ld4 + 0] = f2bf(v.x);
      tile[lk][ld4 + 1] = f2bf(v.y);
      tile[lk][ld4 + 2] = f2bf(v.z);
      tile[lk][ld4 + 3] = f2bf(v.w);
    } else {
      tile[lk][ld4 + 0] = 0; tile[lk][ld4 + 1] = 0;
      tile[lk][ld4 + 2] = 0; tile[lk][ld4 + 3] = 0;
    }
  }
  __syncthreads();
  {
    int ld = t >> 3, lkq = (t & 7) * 4;
    ushort4 o = make_ushort4(tile[lkq + 0][ld], tile[lkq + 1][ld],
                             tile[lkq + 2][ld], tile[lkq + 3][ld]);
    *(ushort4*)(wdT + (size_t)e * DMODEL * KPAD + (size_t)(d0 + ld) * KPAD + k0 + lkq) = o;
  }
}

// ---------------- GEMM1: h = silu(X@wp1)*(X@wp2); dbuf + swizzled LDS ----------------
__global__ __launch_bounds__(256, 2)
void gemm1_kernel(const unsigned short* __restrict__ xb,
                  const unsigned short* __restrict__ wpT,
                  const int* __restrict__ sel,
                  unsigned short* __restrict__ h) {
  const int e = blockIdx.z;
  const int m0 = blockIdx.x * 128;   // m fastest for B-tile L3 reuse
  const int n0 = blockIdx.y * 128;

  __shared__ __align__(16) unsigned short As[2 * 4096];
  __shared__ __align__(16) unsigned short B1s[2 * 4096];
  __shared__ __align__(16) unsigned short B2s[2 * 4096];

  const int t = threadIdx.x;
  const int lane = t & 63;
  const int w = t >> 6;
  const int wm = (w >> 1) * 64;
  const int wn = (w & 1) * 64;
  const int fr = lane & 15;
  const int fq = lane >> 4;
  const int csw = (fq ^ ((fr >> 1) & 3)) * 8;   // swizzled read chunk (elems)

  // staging: thread t covers rows r0 and r0+64, swizzled 8-elem seg
  const int r0 = t >> 2;
  const int sw = ((t & 3) ^ ((t >> 3) & 3)) * 8;  // swizzled global seg (elems)
  const int tok0 = sel[e * CAP + m0 + r0];
  const int tok1 = sel[e * CAP + m0 + 64 + r0];
  const unsigned short* ga0 = xb + (size_t)tok0 * DMODEL + sw;
  const unsigned short* ga1 = xb + (size_t)tok1 * DMODEL + sw;
  const size_t ebase = (size_t)e * HFF2;
  int c0 = n0 + r0;       if (c0 >= HFF) c0 = HFF - 1;   // garbage cols zeroed in epilogue
  int c1 = n0 + 64 + r0;  if (c1 >= HFF) c1 = HFF - 1;
  const unsigned short* gb10 = wpT + (ebase + (size_t)c0) * DMODEL + sw;
  const unsigned short* gb11 = wpT + (ebase + (size_t)c1) * DMODEL + sw;
  const unsigned short* gb20 = wpT + (ebase + (size_t)(HFF + c0)) * DMODEL + sw;
  const unsigned short* gb21 = wpT + (ebase + (size_t)(HFF + c1)) * DMODEL + sw;

  const int dOff = (w * 16) * 32;   // wave-uniform LDS base (elems) within buffer

  f32x4 acc1[4][4], acc2[4][4];
#pragma unroll
  for (int i = 0; i < 4; i++)
#pragma unroll
    for (int j = 0; j < 4; j++) { acc1[i][j] = (f32x4)0.f; acc2[i][j] = (f32x4)0.f; }

  auto stage = [&](int k0, int buf) {
    const int bo = buf * 4096;
    dma16(ga0 + k0, As + bo + dOff);
    dma16(ga1 + k0, As + bo + 2048 + dOff);
    dma16(gb10 + k0, B1s + bo + dOff);
    dma16(gb11 + k0, B1s + bo + 2048 + dOff);
    dma16(gb20 + k0, B2s + bo + dOff);
    dma16(gb21 + k0, B2s + bo + 2048 + dOff);
  };

  stage(0, 0);
  for (int k0 = 0; k0 < DMODEL; k0 += 32) {
    const int cur = (k0 >> 5) & 1;
    __syncthreads();                       // drains cur's DMA; prev reads done
    if (k0 + 32 < DMODEL) stage(k0 + 32, cur ^ 1);  // prefetch overlaps MFMA

    const unsigned short* Ab = As + cur * 4096;
    const unsigned short* B1b = B1s + cur * 4096;
    const unsigned short* B2b = B2s + cur * 4096;
    short8 a[4], b1[4], b2[4];
#pragma unroll
    for (int i = 0; i < 4; i++)
      a[i] = *(const short8*)(Ab + (wm + i * 16 + fr) * 32 + csw);
#pragma unroll
    for (int j = 0; j < 4; j++) {
      b1[j] = *(const short8*)(B1b + (wn + j * 16 + fr) * 32 + csw);
      b2[j] = *(const short8*)(B2b + (wn + j * 16 + fr) * 32 + csw);
    }
#pragma unroll
    for (int i = 0; i < 4; i++)
#pragma unroll
      for (int j = 0; j < 4; j++) {
        acc1[i][j] = __builtin_amdgcn_mfma_f32_16x16x32_bf16(a[i], b1[j], acc1[i][j], 0, 0, 0);
        acc2[i][j] = __builtin_amdgcn_mfma_f32_16x16x32_bf16(a[i], b2[j], acc2[i][j], 0, 0, 0);
      }
  }

#pragma unroll
  for (int i = 0; i < 4; i++) {
#pragma unroll
    for (int j = 0; j < 4; j++) {
      const int col = n0 + wn + j * 16 + fr;
      if (col < KPAD) {
#pragma unroll
        for (int r = 0; r < 4; r++) {
          const int row = m0 + wm + i * 16 + fq * 4 + r;
          float v1 = acc1[i][j][r], v2 = acc2[i][j][r];
          float hv = (col < HFF) ? (v1 / (1.f + __expf(-v1))) * v2 : 0.f;
          h[((size_t)e * CAP + row) * KPAD + col] = f2bf(hv);
        }
      }
    }
  }
}

// ---------------- GEMM2: contrib[e][slot] = h @ wd (no gate, no atomics) ----------------
__global__ __launch_bounds__(256, 3)
void gemm2_kernel(const unsigned short* __restrict__ h,
                  const unsigned short* __restrict__ wdT,
                  unsigned short* __restrict__ contrib) {
  const int e = blockIdx.z;
  const int m0 = blockIdx.x * 128;
  const int n0 = blockIdx.y * 128;

  __shared__ __align__(16) unsigned short As[2 * 4096];
  __shared__ __align__(16) unsigned short Bs[2 * 4096];

  const int t = threadIdx.x;
  const int lane = t & 63;
  const int w = t >> 6;
  const int wm = (w >> 1) * 64;
  const int wn = (w & 1) * 64;
  const int fr = lane & 15;
  const int fq = lane >> 4;
  const int csw = (fq ^ ((fr >> 1) & 3)) * 8;

  const int r0 = t >> 2;
  const int sw = ((t & 3) ^ ((t >> 3) & 3)) * 8;
  const unsigned short* ga0 = h + ((size_t)e * CAP + m0 + r0) * KPAD + sw;
  const unsigned short* ga1 = h + ((size_t)e * CAP + m0 + 64 + r0) * KPAD + sw;
  const unsigned short* gb0 = wdT + ((size_t)e * DMODEL + n0 + r0) * KPAD + sw;
  const unsigned short* gb1 = wdT + ((size_t)e * DMODEL + n0 + 64 + r0) * KPAD + sw;

  const int dOff = (w * 16) * 32;

  f32x4 acc[4][4];
#pragma unroll
  for (int i = 0; i < 4; i++)
#pragma unroll
    for (int j = 0; j < 4; j++) acc[i][j] = (f32x4)0.f;

  auto stage = [&](int k0, int buf) {
    const int bo = buf * 4096;
    dma16(ga0 + k0, As + bo + dOff);
    dma16(ga1 + k0, As + bo + 2048 + dOff);
    dma16(gb0 + k0, Bs + bo + dOff);
    dma16(gb1 + k0, Bs + bo + 2048 + dOff);
  };

  stage(0, 0);
  for (int k0 = 0; k0 < KPAD; k0 += 32) {
    const int cur = (k0 >> 5) & 1;
    __syncthreads();
    if (k0 + 32 < KPAD) stage(k0 + 32, cur ^ 1);

    const unsigned short* Ab = As + cur * 4096;
    const unsigned short* Bb = Bs + cur * 4096;
    short8 a[4], b[4];
#pragma unroll
    for (int i = 0; i < 4; i++)
      a[i] = *(const short8*)(Ab + (wm + i * 16 + fr) * 32 + csw);
#pragma unroll
    for (int j = 0; j < 4; j++)
      b[j] = *(const short8*)(Bb + (wn + j * 16 + fr) * 32 + csw);
#pragma unroll
    for (int i = 0; i < 4; i++)
#pragma unroll
      for (int j = 0; j < 4; j++)
        acc[i][j] = __builtin_amdgcn_mfma_f32_16x16x32_bf16(a[i], b[j], acc[i][j], 0, 0, 0);
  }

#pragma unroll
  for (int i = 0; i < 4; i++) {
#pragma unroll
    for (int j = 0; j < 4; j++) {
      const int col = n0 + wn + j * 16 + fr;
#pragma unroll
      for (int r = 0; r < 4; r++) {
        const int row = m0 + wm + i * 16 + fq * 4 + r;
        contrib[((size_t)e * CAP + row) * DMODEL + col] = f2bf(acc[i][j][r]);
      }
    }
  }
}

// ---------------- Combine: out[tok] = g0*contrib[e0][s0] + g1*contrib[e1][s1] ----------------
__global__ void combine_kernel(const unsigned short* __restrict__ contrib,
                               const int* __restrict__ topi,
                               const int* __restrict__ slot,
                               const float* __restrict__ gates,
                               float* __restrict__ out) {
  const int tok = blockIdx.x;
  const int t = threadIdx.x;
  const int e0 = topi[2 * tok], e1 = topi[2 * tok + 1];
  const int s0 = slot[2 * tok], s1 = slot[2 * tok + 1];
  const float g0 = gates[2 * tok], g1 = gates[2 * tok + 1];
  float4 acc = make_float4(0.f, 0.f, 0.f, 0.f);
  if (s0 >= 0) {
    ushort4 c = *(const ushort4*)(contrib + ((size_t)(e0 * CAP + s0)) * DMODEL + t * 4);
    acc.x += g0 * bf2f(c.x); acc.y += g0 * bf2f(c.y);
    acc.z += g0 * bf2f(c.z); acc.w += g0 * bf2f(c.w);
  }
  if (s1 >= 0) {
    ushort4 c = *(const ushort4*)(contrib + ((size_t)(e1 * CAP + s1)) * DMODEL + t * 4);
    acc.x += g1 * bf2f(c.x); acc.y += g1 * bf2f(c.y);
    acc.z += g1 * bf2f(c.z); acc.w += g1 * bf2f(c.w);
  }
  *(float4*)(out + (size_t)tok * DMODEL + t * 4) = acc;
}

// ---------------- launch ----------------
extern "C" void kernel_launch(void* const* d_in, const int* in_sizes, int n_in,
                              void* d_out, int out_size, void* d_ws, size_t ws_size,
                              hipStream_t stream) {
  const float* x = (const float*)d_in[0];
  const float* noise = (const float*)d_in[1];
  const float* w_route = (const float*)d_in[2];
  const float* b_route = (const float*)d_in[3];
  const float* w_noise = (const float*)d_in[4];
  const float* b_noise = (const float*)d_in[5];
  const float* w_proj = (const float*)d_in[6];
  const float* w_down = (const float*)d_in[7];
  float* out = (float*)d_out;

  char* ws = (char*)d_ws;
  const size_t WT_BYTES = (size_t)NEXP * HFF2 * DMODEL * 2;   // 89.4 MB (wpT; later wdT+contrib)
  const size_t WDT_BYTES = (size_t)NEXP * DMODEL * KPAD * 2;  // 45.1 MB
  const size_t H_BYTES = (size_t)NEXP * CAP * KPAD * 2;       // 90.2 MB
  unsigned short* wT = (unsigned short*)ws;
  unsigned short* contrib = (unsigned short*)(ws + WDT_BYTES);  // 33.5 MB, dead tail of wT region
  unsigned short* hbuf = (unsigned short*)(ws + WT_BYTES);
  char* p = ws + WT_BYTES + H_BYTES;
  int* sel = (int*)p;          p += (size_t)NEXP * CAP * 4;
  float* gsel = (float*)p;     p += (size_t)NEXP * CAP * 4;
  int* topi = (int*)p;         p += (size_t)NTOK * 2 * 4;
  float* gates = (float*)p;    p += (size_t)NTOK * 2 * 4;
  int* slot = (int*)p;

  // xb (bf16 x, 16.8 MB) lives in d_out until gemm1 done; combine overwrites out fully.
  unsigned short* xb = (unsigned short*)d_out;

  hipLaunchKernelGGL(cast_x_kernel, dim3(NTOK * DMODEL / (256 * 8)), dim3(256), 0, stream, x, xb);
  hipLaunchKernelGGL(router_kernel, dim3(NTOK / 4), dim3(256), 0, stream,
                     x, noise, w_route, b_route, w_noise, b_noise, topi, gates);
  hipLaunchKernelGGL(dispatch_kernel, dim3(NEXP), dim3(1024), 0, stream, topi, gates, sel, gsel, slot);
  hipLaunchKernelGGL(transpose_wp_kernel, dim3(171, 32, NEXP), dim3(256), 0, stream, w_proj, wT);
  hipLaunchKernelGGL(gemm1_kernel, dim3(16, 22, NEXP), dim3(256), 0, stream, xb, wT, sel, hbuf);
  hipLaunchKernelGGL(transpose_wd_kernel, dim3(KPAD / 32, DMODEL / 32, NEXP), dim3(256), 0, stream, w_down, wT);
  hipLaunchKernelGGL(gemm2_kernel, dim3(16, DMODEL / 128, NEXP), dim3(256), 0, stream,
                     hbuf, wT, contrib);
  hipLaunchKernelGGL(combine_kernel, dim3(NTOK), dim3(256), 0, stream,
                     contrib, topi, slot, gates, out);
  hipLaunchKernelGGL(aux_kernel, dim3(1), dim3(256), 0, stream, topi, gates, out);
}